// Round 8
// baseline (268.860 us; speedup 1.0000x reference)
//
#include <hip/hip_runtime.h>

// Reference reduces to: out = box3x3_zeropad(x) + x + bias[c]
// (softmax over a size-1 axis == 1.0; the w1/w2 matmul branch is dead).
//
// History: R2 LDS-staged 82.5us, R3 register-march 81.2us, R7 flat
// full-occupancy 86us -- three unrelated structures, same time, all with
// VALUBusy<=15% and HBM ~2.4 TB/s. Writes alone reach 6.5 TB/s (fill), so
// the cap is on the READ side. This round is a decisive A/B:
//   dispatch 1: copy_probe (out = x, 268 MB R+W) -> environment ceiling
//   dispatch 2: stencil with 4 loads / 2 outputs per thread (read
//               amplification 2x instead of 3x, 4 KB in flight per wave)
// Stencil runs LAST so d_out is correct for validation.

#define WW 64

__device__ __forceinline__ float dpp_shr1(float x) {
    // lane i <- lane i-1 within each 16-lane DPP row; first lane of row -> 0
    return __int_as_float(__builtin_amdgcn_update_dpp(
        0, __float_as_int(x), 0x111, 0xF, 0xF, true));
}
__device__ __forceinline__ float dpp_shl1(float x) {
    // lane i <- lane i+1 within each 16-lane DPP row; last lane of row -> 0
    return __int_as_float(__builtin_amdgcn_update_dpp(
        0, __float_as_int(x), 0x101, 0xF, 0xF, true));
}

// horizontal 3-tap box sum of a 64-col row distributed as 16 lanes x float4
__device__ __forceinline__ float4 hsum3(float4 v) {
    float lft = dpp_shr1(v.w);   // col-1 (left neighbor's .w; 0 at plane edge)
    float rgt = dpp_shl1(v.x);   // col+4 (right neighbor's .x; 0 at plane edge)
    float t1 = v.x + v.y;
    float t2 = v.y + v.z;
    float t3 = v.z + v.w;
    float4 h;
    h.x = lft + t1;
    h.y = t1 + v.z;
    h.z = t2 + v.w;
    h.w = t3 + rgt;
    return h;
}

// ---- A/B probe: pure streaming copy, same footprint as ideal stencil ----
__global__ __launch_bounds__(256) void copy_probe_kernel(
    const float4* __restrict__ in, float4* __restrict__ out)
{
    size_t i = (size_t)blockIdx.x * 256 + threadIdx.x;
    out[i] = in[i];
}

// ---- stencil: 1 thread = 2 vertically-adjacent float4 outputs ----
__global__ __launch_bounds__(256) void dwconv_flat2_kernel(
    const float* __restrict__ x,
    const float* __restrict__ bias,
    float* __restrict__ out)
{
    // gid -> (plane, row-pair, seg): 8192 planes x 32 row-pairs x 16 segs.
    // 512 gids/plane -> wave (64 gids) never straddles a plane: bias load is
    // wave-uniform (scalar), and each 16-lane DPP group holds one full
    // 64-col image row -> DPP halo semantics exact.
    const int gid   = blockIdx.x * 256 + threadIdx.x;   // 0..4194303
    const int plane = gid >> 9;
    const int rp    = (gid >> 4) & 31;                  // row pair 0..31
    const int seg   = gid & 15;
    const int r0    = rp << 1;                          // first output row

    const float* xp = x + ((size_t)plane << 12) + (r0 << 6) + (seg << 2);

    const float4 zero = make_float4(0.f, 0.f, 0.f, 0.f);
    // four independent loads (rows r0-1, r0, r0+1, r0+2), issued before use
    float4 vA = (rp > 0)  ? *reinterpret_cast<const float4*>(xp - WW)     : zero;
    float4 vB =             *reinterpret_cast<const float4*>(xp);
    float4 vC =             *reinterpret_cast<const float4*>(xp + WW);
    float4 vD = (rp < 31) ? *reinterpret_cast<const float4*>(xp + 2 * WW) : zero;

    float4 hA = hsum3(vA);
    float4 hB = hsum3(vB);
    float4 hC = hsum3(vC);
    float4 hD = hsum3(vD);

    const float bv = bias[plane & 255];

    float4 o0, o1;
    o0.x = hA.x + hB.x + hC.x + vB.x + bv;
    o0.y = hA.y + hB.y + hC.y + vB.y + bv;
    o0.z = hA.z + hB.z + hC.z + vB.z + bv;
    o0.w = hA.w + hB.w + hC.w + vB.w + bv;
    o1.x = hB.x + hC.x + hD.x + vC.x + bv;
    o1.y = hB.y + hC.y + hD.y + vC.y + bv;
    o1.z = hB.z + hC.z + hD.z + vC.z + bv;
    o1.w = hB.w + hC.w + hD.w + vC.w + bv;

    float* op = out + ((size_t)plane << 12) + (r0 << 6) + (seg << 2);
    *reinterpret_cast<float4*>(op)      = o0;
    *reinterpret_cast<float4*>(op + WW) = o1;
}

extern "C" void kernel_launch(void* const* d_in, const int* in_sizes, int n_in,
                              void* d_out, int out_size, void* d_ws, size_t ws_size,
                              hipStream_t stream)
{
    const float* x    = (const float*)d_in[0];
    // d_in[1..4] = w1, b1, w2, b2 : algebraically dead (softmax over size-1 axis == 1)
    const float* bias = (const float*)d_in[5];
    float* out        = (float*)d_out;

    // Probe first (its result is overwritten by the real kernel below).
    // 33,554,432 floats = 8,388,608 float4 = 32768 blocks of 256.
    copy_probe_kernel<<<32768, 256, 0, stream>>>(
        (const float4*)x, (float4*)out);

    // Real stencil: 8192 planes * 32 row-pairs * 16 segs = 4,194,304 threads
    // = 16384 blocks of 256.
    dwconv_flat2_kernel<<<16384, 256, 0, stream>>>(x, bias, out);
}